// Round 17
// baseline (242.665 us; speedup 1.0000x reference)
//
#include <hip/hip_runtime.h>
#include <math.h>

#define N_INIT 20000
#define LVLS   32
#define PP     1024
#define DD     64
#define DEE    128
#define N_TOT  (N_INIT + LVLS * PP)   // 52768
#define ND     (LVLS * PP)            // 32768 derived nodes
#define NBLK   1024                   // 4 blocks/CU (launch_bounds), 1 node/block/level
#define NTHR   256
#define NTILES ((N_TOT + 63) / 64)    // 825 eval tiles

// ws layout:
// [0,256) ctl: acc_i[4]@0, acc_f@16, init_done@20, fin_done@24
// [256, 256+ND*DD*4)  dstore (memset 0xFF each call: negative-NaN sentinel)
#define DSTORE_OFF 256

typedef unsigned long long ull;
union F2U { ull u; float2 f; };
#define SENT_MASK 0x8000000080000000ULL
#define SIGN_CLR  0x7FFFFFFF7FFFFFFFULL

// ---- device-coherent accessors (AGENT scope), proven r5-r16 ----
__device__ __forceinline__ int ldi(const int* p) {
    return __hip_atomic_load(p, __ATOMIC_RELAXED, __HIP_MEMORY_SCOPE_AGENT);
}
__device__ __forceinline__ float ldf(const float* p) {
    return __hip_atomic_load(p, __ATOMIC_RELAXED, __HIP_MEMORY_SCOPE_AGENT);
}
__device__ __forceinline__ ull ldull(const ull* p) {
    return __hip_atomic_load(p, __ATOMIC_RELAXED, __HIP_MEMORY_SCOPE_AGENT);
}
__device__ __forceinline__ void stull(ull* p, ull v) {
    __hip_atomic_store(p, v, __ATOMIC_RELAXED, __HIP_MEMORY_SCOPE_AGENT);
}
__device__ __forceinline__ void vm0() {
    asm volatile("s_waitcnt vmcnt(0)" ::: "memory");
}
__device__ __forceinline__ float softplusf(float x) {
    return fmaxf(x, 0.f) + log1pf(expf(-fabsf(x)));
}
// blocking read of a published float2 (r11-proven): cached try, coherent spin fallback
__device__ __forceinline__ float2 ld_hyb(const ull* p) {
    F2U cv;
    cv.u = *p;
    if (cv.u & SENT_MASK) {
        cv.u = ldull(p);
        while (cv.u & SENT_MASK) {
            __builtin_amdgcn_s_sleep(1);
            cv.u = ldull(p);
        }
    }
    return cv.f;
}

__global__ __launch_bounds__(NTHR, 4) void persist13(
    const int* __restrict__ thax, const int* __restrict__ parents,
    const int* __restrict__ rules, const int* __restrict__ sel_mask,
    const int* __restrict__ good_mask, const float* __restrict__ init_table,
    const float* __restrict__ W_rule, const float* __restrict__ b_rule,
    const float* __restrict__ W1, const float* __restrict__ b1,
    const float* __restrict__ w2, const float* __restrict__ b2,
    char* __restrict__ ws, float* __restrict__ out)
{
    int*   acc_i     = (int*)ws;
    float* acc_f     = (float*)(ws + 16);
    int*   init_done = (int*)(ws + 20);
    int*   fin_done  = (int*)(ws + 24);
    ull*   dstore_u  = (ull*)(ws + DSTORE_OFF);

    const int b = blockIdx.x, t = threadIdx.x;
    const int lane = t & 63, wv = t >> 6;

    __shared__ float peL[2][2 * DD];        // 1 KB (depth-2 pipeline buffers, 1 node)
    __shared__ float partial[2][4][DD];     // 2 KB (double-buffered by level parity)
    __shared__ float sS[64][DD];            // 16 KB (eval)
    __shared__ float logitL[64];

    // ---------------- phase 1: mask counts ----------------
    {
        int idx = b * NTHR + t;
        bool v = idx < N_TOT;
        bool sel  = v && sel_mask[idx] > 0;
        bool good = sel && good_mask[idx] > 0;
        unsigned long long ms = __ballot(sel), mg = __ballot(good);
        if (lane == 0) {
            if (mg) atomicAdd(&acc_i[0], (int)__popcll(mg));
            if (ms) atomicAdd(&acc_i[1], (int)__popcll(ms));
        }
    }
    vm0();
    __syncthreads();
    if (t == 0) atomicAdd(init_done, 1);

    // ---------------- phase 2: depth-2 pipelined level loop, 1 node/block ----------------
    const int nd = b;                       // node owned within every level
    bool pend0 = false, pend1 = false;
    int  pid0 = 0,      pid1 = 0;
    const int grow = t >> 5, gj = t & 31;   // gather thread's (parent row, float2-elem), t<64

    // prologue: gather level 0 (blocking-free: all parents < N_INIT)
    if (t < 64) {
        int pid = parents[(size_t)nd * 2 + grow];
        float2 v = ((const float2*)init_table)[(size_t)thax[pid] * 32 + gj];
        ((float2*)&peL[0][grow * DD])[gj] = v;
    }
    // prologue: speculative gather level 1 (non-blocking)
    if (t < 64) {
        int pid = parents[((size_t)PP + nd) * 2 + grow];
        F2U cv; bool bad = false;
        if (pid < N_INIT) {
            cv.f = ((const float2*)init_table)[(size_t)thax[pid] * 32 + gj];
        } else {
            cv.u = ldull(&dstore_u[(size_t)(pid - N_INIT) * 32 + gj]);
            bad = (cv.u & SENT_MASK) != 0ull;
        }
        ((float2*)&peL[1][grow * DD])[gj] = cv.f;
        pend1 = bad; pid1 = pid;
    }

    for (int l = 0; l < LVLS; ++l) {
        const int par = l & 1;
        // fixup: re-fetch stale words of this level's buffer (rare; bounded spin)
        if (t < 64) {
            bool pend = par ? pend1 : pend0;
            if (pend) {
                int pid = par ? pid1 : pid0;
                float2 v = ld_hyb(&dstore_u[(size_t)(pid - N_INIT) * 32 + gj]);
                ((float2*)&peL[par][grow * DD])[gj] = v;
                if (par) pend1 = false; else pend0 = false;
            }
        }
        __syncthreads();                       // peL[par] final
        // compute: wave wv covers rows [wv*32, wv*32+32) (r2-proven wave split)
        {
            const int ru = rules[l * PP + nd];
            const float4* __restrict__ W4 = (const float4*)W_rule + (size_t)ru * 2048;
            const int q = lane & 15, r = lane >> 4;
            float4 acc = make_float4(0.f, 0.f, 0.f, 0.f);
#pragma unroll
            for (int i = 0; i < 8; ++i) {
                int row = wv * 32 + i * 4 + r;
                float4 w = W4[row * 16 + q];
                float  s = peL[par][row];
                acc.x = fmaf(s, w.x, acc.x);
                acc.y = fmaf(s, w.y, acc.y);
                acc.z = fmaf(s, w.z, acc.z);
                acc.w = fmaf(s, w.w, acc.w);
            }
#pragma unroll
            for (int off = 16; off <= 32; off <<= 1) {
                acc.x += __shfl_xor(acc.x, off, 64);
                acc.y += __shfl_xor(acc.y, off, 64);
                acc.z += __shfl_xor(acc.z, off, 64);
                acc.w += __shfl_xor(acc.w, off, 64);
            }
            if (r == 0) *(float4*)&partial[par][wv][4 * q] = acc;
        }
        __syncthreads();                       // partial ready; peL[par] consumed
        // publish (sign-cleared sc1) ...
        if (t < 32) {
            const int j2 = t, jj = t * 2;
            const int ru = rules[l * PP + nd];
            float h0 = partial[par][0][jj]     + partial[par][1][jj]
                     + partial[par][2][jj]     + partial[par][3][jj]
                     + b_rule[ru * DD + jj];
            float h1 = partial[par][0][jj + 1] + partial[par][1][jj + 1]
                     + partial[par][2][jj + 1] + partial[par][3][jj + 1]
                     + b_rule[ru * DD + jj + 1];
            F2U cv;
            cv.f.x = fmaxf(h0, 0.f);
            cv.f.y = fmaxf(h1, 0.f);
            cv.u &= SIGN_CLR;          // published sign bits must be 0
            stull(&dstore_u[((size_t)l * PP + nd) * 32 + j2], cv.u);
        }
        // ... overlapped with speculative gather of level l+2 into buf[par]
        if (l + 2 < LVLS && t < 64) {
            int pid = parents[((size_t)(l + 2) * PP + nd) * 2 + grow];
            F2U cv; bool bad = false;
            if (pid < N_INIT) {
                cv.f = ((const float2*)init_table)[(size_t)thax[pid] * 32 + gj];
            } else {
                cv.u = ldull(&dstore_u[(size_t)(pid - N_INIT) * 32 + gj]);
                bad = (cv.u & SENT_MASK) != 0ull;
            }
            ((float2*)&peL[par][grow * DD])[gj] = cv.f;
            if (par) { pend1 = bad; pid1 = pid; }
            else     { pend0 = bad; pid0 = pid; }
        }
    }

    // ---------------- phase 3: gate on mask counts ----------------
    if (t == 0) { while (ldi(init_done) < NBLK) __builtin_amdgcn_s_sleep(1); }
    __syncthreads();
    const int ng = ldi(&acc_i[0]);
    const int ns = ldi(&acc_i[1]);
    const int nn = ns - ng;
    const float pos_w = ng > 0 ? 0.85f / (float)ng : 1.0f;
    const float neg_w = nn > 0 ? 0.15f / (float)nn : 1.0f;

    // ---------------- phase 4: eval + loss (r11/r15 verbatim) ----------------
    const int g  = t & 31;
    const int n0 = t >> 5;
    const float4* __restrict__ W14 = (const float4*)W1;
    const float4 b1v = ((const float4*)b1)[g];
    const float4 w2v = ((const float4*)w2)[g];
    const float  b2v = b2[0];

    float loss = 0.f;
    int cp = 0, cn = 0;

    for (int tile = b; tile < NTILES; tile += NBLK) {
        const int base = tile * 64;
        const int nv = (N_TOT - base < 64) ? (N_TOT - base) : 64;
        for (int idx = t; idx < 64 * 32; idx += NTHR) {
            int n = idx >> 5, j = idx & 31;
            int node = base + n;
            float2 v = make_float2(0.f, 0.f);
            if (n < nv) {
                if (node < N_INIT)
                    v = ((const float2*)init_table)[(size_t)thax[node] * 32 + j];
                else
                    v = ld_hyb(&dstore_u[(size_t)(node - N_INIT) * 32 + j]);
            }
            ((float2*)sS[n])[j] = v;
        }
        __syncthreads();

        float4 a[8];
#pragma unroll
        for (int k = 0; k < 8; ++k) a[k] = b1v;
#pragma unroll
        for (int d4 = 0; d4 < 16; ++d4) {
            float4 w0  = W14[(d4 * 4 + 0) * 32 + g];
            float4 w1  = W14[(d4 * 4 + 1) * 32 + g];
            float4 w2q = W14[(d4 * 4 + 2) * 32 + g];
            float4 w3  = W14[(d4 * 4 + 3) * 32 + g];
#pragma unroll
            for (int k = 0; k < 8; ++k) {
                float4 s = ((const float4*)sS[n0 + 8 * k])[d4];
                a[k].x = fmaf(s.x, w0.x, a[k].x); a[k].y = fmaf(s.x, w0.y, a[k].y);
                a[k].z = fmaf(s.x, w0.z, a[k].z); a[k].w = fmaf(s.x, w0.w, a[k].w);
                a[k].x = fmaf(s.y, w1.x, a[k].x); a[k].y = fmaf(s.y, w1.y, a[k].y);
                a[k].z = fmaf(s.y, w1.z, a[k].z); a[k].w = fmaf(s.y, w1.w, a[k].w);
                a[k].x = fmaf(s.z, w2q.x, a[k].x); a[k].y = fmaf(s.z, w2q.y, a[k].y);
                a[k].z = fmaf(s.z, w2q.z, a[k].z); a[k].w = fmaf(s.z, w2q.w, a[k].w);
                a[k].x = fmaf(s.w, w3.x, a[k].x); a[k].y = fmaf(s.w, w3.y, a[k].y);
                a[k].z = fmaf(s.w, w3.z, a[k].z); a[k].w = fmaf(s.w, w3.w, a[k].w);
            }
        }
        float p[8];
#pragma unroll
        for (int k = 0; k < 8; ++k) {
            p[k] = fmaxf(a[k].x, 0.f) * w2v.x + fmaxf(a[k].y, 0.f) * w2v.y +
                   fmaxf(a[k].z, 0.f) * w2v.z + fmaxf(a[k].w, 0.f) * w2v.w;
#pragma unroll
            for (int off = 1; off < 32; off <<= 1)
                p[k] += __shfl_xor(p[k], off, 32);
        }
        if (g == 0) {
#pragma unroll
            for (int k = 0; k < 8; ++k)
                logitL[n0 + 8 * k] = p[k] + b2v;
        }
        __syncthreads();

        if (t < 64) {
            int node = base + t;
            bool valid = t < nv;
            float lg = logitL[t];
            bool sel  = valid && sel_mask[node] > 0;
            bool good = sel && good_mask[node] > 0;
            float bce = softplusf(lg) - lg * (good ? 1.f : 0.f);
            float w   = (good ? pos_w : neg_w) * (sel ? 1.f : 0.f);
            loss += valid ? w * bce : 0.f;
            cp += (good && lg >= 0.f) ? 1 : 0;
            cn += (sel && !good && lg < 0.f) ? 1 : 0;
        }
        __syncthreads();
    }

    // ---------------- phase 5: reduce + finalize (r15 verbatim) ----------------
    if (t < 64) {
        float c = loss;
        int cpp = cp, cnn = cn;
#pragma unroll
        for (int off = 32; off; off >>= 1) {
            c   += __shfl_down(c, off, 64);
            cpp += __shfl_down(cpp, off, 64);
            cnn += __shfl_down(cnn, off, 64);
        }
        if (t == 0) {
            atomicAdd(acc_f, c);
            if (cpp) atomicAdd(&acc_i[2], cpp);
            if (cnn) atomicAdd(&acc_i[3], cnn);
            vm0();
            int d = atomicAdd(fin_done, 1);
            if (d == NBLK - 1) {
                int ng2 = ldi(&acc_i[0]);
                int ns2 = ldi(&acc_i[1]);
                int cp2 = ldi(&acc_i[2]);
                int cn2 = ldi(&acc_i[3]);
                float lf = ldf(acc_f);
                int nn2 = ns2 - ng2;
                out[0] = lf;
                out[1] = ng2 > 0 ? (float)cp2 / (float)ng2 : 1.0f;
                out[2] = nn2 > 0 ? (float)cn2 / (float)nn2 : 1.0f;
            }
        }
    }
}

extern "C" void kernel_launch(void* const* d_in, const int* in_sizes, int n_in,
                              void* d_out, int out_size, void* d_ws, size_t ws_size,
                              hipStream_t stream) {
    const int*   thax       = (const int*)d_in[0];
    const int*   parents    = (const int*)d_in[1];
    const int*   rules      = (const int*)d_in[2];
    const int*   sel_mask   = (const int*)d_in[3];
    const int*   good_mask  = (const int*)d_in[4];
    const float* init_table = (const float*)d_in[5];
    const float* W_rule     = (const float*)d_in[6];
    const float* b_rule     = (const float*)d_in[7];
    const float* W1         = (const float*)d_in[8];
    const float* b1         = (const float*)d_in[9];
    const float* w2         = (const float*)d_in[10];
    const float* b2         = (const float*)d_in[11];

    // ctl -> 0 ; dstore -> 0xFF (negative-NaN sentinel, sign bit 1)
    hipMemsetAsync(d_ws, 0, 256, stream);
    hipMemsetAsync((char*)d_ws + DSTORE_OFF, 0xFF, (size_t)ND * DD * 4, stream);

    persist13<<<NBLK, NTHR, 0, stream>>>(
        thax, parents, rules, sel_mask, good_mask, init_table,
        W_rule, b_rule, W1, b1, w2, b2,
        (char*)d_ws, (float*)d_out);
}

// Round 18
// 200.171 us; speedup vs baseline: 1.2123x; 1.2123x over previous
//
#include <hip/hip_runtime.h>
#include <math.h>

#define N_INIT 20000
#define LVLS   32
#define PP     1024
#define DD     64
#define DEE    128
#define N_TOT  (N_INIT + LVLS * PP)   // 52768
#define ND     (LVLS * PP)            // 32768 derived nodes
#define NBLK   512                    // 2 blocks/CU: proven optimum (r8/r15 vs r7/r17)
#define NTHR   256
#define NPB    2                      // nodes per block per level
#define NTILES ((N_TOT + 63) / 64)    // 825 eval tiles

// ws layout:
// [0,256) ctl: acc_i[4]@0, acc_f@16, init_done@20, fin_done@24, tile_claim@28
// [256, 256+ND*DD*4)  dstore (memset 0xFF each call: negative-NaN sentinel)
#define DSTORE_OFF 256

typedef unsigned long long ull;
union F2U { ull u; float2 f; };
#define SENT_MASK 0x8000000080000000ULL
#define SIGN_CLR  0x7FFFFFFF7FFFFFFFULL

// ---- device-coherent accessors (AGENT scope), proven r5-r17 ----
__device__ __forceinline__ int ldi(const int* p) {
    return __hip_atomic_load(p, __ATOMIC_RELAXED, __HIP_MEMORY_SCOPE_AGENT);
}
__device__ __forceinline__ float ldf(const float* p) {
    return __hip_atomic_load(p, __ATOMIC_RELAXED, __HIP_MEMORY_SCOPE_AGENT);
}
__device__ __forceinline__ ull ldull(const ull* p) {
    return __hip_atomic_load(p, __ATOMIC_RELAXED, __HIP_MEMORY_SCOPE_AGENT);
}
__device__ __forceinline__ void stull(ull* p, ull v) {
    __hip_atomic_store(p, v, __ATOMIC_RELAXED, __HIP_MEMORY_SCOPE_AGENT);
}
__device__ __forceinline__ void vm0() {
    asm volatile("s_waitcnt vmcnt(0)" ::: "memory");
}
__device__ __forceinline__ float softplusf(float x) {
    return fmaxf(x, 0.f) + log1pf(expf(-fabsf(x)));
}
// blocking read of a published float2 (r11-proven): cached try, coherent spin fallback
__device__ __forceinline__ float2 ld_hyb(const ull* p) {
    F2U cv;
    cv.u = *p;
    if (cv.u & SENT_MASK) {
        cv.u = ldull(p);
        while (cv.u & SENT_MASK) {
            __builtin_amdgcn_s_sleep(1);
            cv.u = ldull(p);
        }
    }
    return cv.f;
}

__global__ __launch_bounds__(NTHR, 2) void persist14(
    const int* __restrict__ thax, const int* __restrict__ parents,
    const int* __restrict__ rules, const int* __restrict__ sel_mask,
    const int* __restrict__ good_mask, const float* __restrict__ init_table,
    const float* __restrict__ W_rule, const float* __restrict__ b_rule,
    const float* __restrict__ W1, const float* __restrict__ b1,
    const float* __restrict__ w2, const float* __restrict__ b2,
    char* __restrict__ ws, float* __restrict__ out)
{
    int*   acc_i      = (int*)ws;
    float* acc_f      = (float*)(ws + 16);
    int*   init_done  = (int*)(ws + 20);
    int*   fin_done   = (int*)(ws + 24);
    int*   tile_claim = (int*)(ws + 28);
    ull*   dstore_u   = (ull*)(ws + DSTORE_OFF);

    const int b = blockIdx.x, t = threadIdx.x;
    const int lane = t & 63, wv = t >> 6;

    __shared__ float peL[2][NPB][2 * DD];   // 2 KB (depth-2 pipeline buffers)
    __shared__ float partial[2][4][DD];     // 2 KB (double-buffered by level parity)
    __shared__ float sS[64][DD];            // 16 KB (eval)
    __shared__ float logitL[64];
    __shared__ int   s_tile;

    // ---------------- phase 1: mask counts (r9 verbatim) ----------------
    {
        int idx = b * NTHR + t;
        bool v = idx < N_TOT;
        bool sel  = v && sel_mask[idx] > 0;
        bool good = sel && good_mask[idx] > 0;
        unsigned long long ms = __ballot(sel), mg = __ballot(good);
        if (lane == 0) {
            if (mg) atomicAdd(&acc_i[0], (int)__popcll(mg));
            if (ms) atomicAdd(&acc_i[1], (int)__popcll(ms));
        }
    }
    vm0();
    __syncthreads();
    if (t == 0) atomicAdd(init_done, 1);

    // ---------------- phase 2: depth-2 pipelined level loop (r15 verbatim) ----------------
    const int nb0 = b * NPB;
    bool pend0 = false, pend1 = false;
    int  pid0 = 0,      pid1 = 0;
    const int grow = t >> 5, gj = t & 31;   // gather thread's (row, float2-elem)

    // prologue: gather level 0 (blocking-free: all parents < N_INIT)
    if (t < 128) {
        int pid = parents[(size_t)nb0 * 2 + grow];
        float2 v = ((const float2*)init_table)[(size_t)thax[pid] * 32 + gj];
        ((float2*)&peL[0][grow >> 1][(grow & 1) * DD])[gj] = v;
    }
    // prologue: speculative gather level 1 into buf1 (non-blocking)
    if (t < 128) {
        int pid = parents[((size_t)PP + nb0) * 2 + grow];
        F2U cv; bool bad = false;
        if (pid < N_INIT) {
            cv.f = ((const float2*)init_table)[(size_t)thax[pid] * 32 + gj];
        } else {
            cv.u = ldull(&dstore_u[(size_t)(pid - N_INIT) * 32 + gj]);
            bad = (cv.u & SENT_MASK) != 0ull;
        }
        ((float2*)&peL[1][grow >> 1][(grow & 1) * DD])[gj] = cv.f;
        pend1 = bad; pid1 = pid;
    }

    for (int l = 0; l < LVLS; ++l) {
        const int par = l & 1;
        // fixup: re-fetch stale words of this level's buffer (rare; bounded spin)
        if (t < 128) {
            bool pend = par ? pend1 : pend0;
            if (pend) {
                int pid = par ? pid1 : pid0;
                float2 v = ld_hyb(&dstore_u[(size_t)(pid - N_INIT) * 32 + gj]);
                ((float2*)&peL[par][grow >> 1][(grow & 1) * DD])[gj] = v;
                if (par) pend1 = false; else pend0 = false;
            }
        }
        __syncthreads();                       // peL[par] final
        // compute: waves {0,1}->node 0, {2,3}->node 1; half = wv&1 covers 64 rows
        {
            const int nv = wv >> 1, half = wv & 1;
            const int ru = rules[l * PP + nb0 + nv];
            const float4* __restrict__ W4 =
                (const float4*)W_rule + (size_t)ru * 2048 + (size_t)half * 64 * 16;
            const int q = lane & 15, r = lane >> 4;
            const float* pk = &peL[par][nv][half * DD];
            float4 acc = make_float4(0.f, 0.f, 0.f, 0.f);
#pragma unroll
            for (int i = 0; i < 16; ++i) {
                float4 w = W4[(i * 4 + r) * 16 + q];
                float  s = pk[i * 4 + r];
                acc.x = fmaf(s, w.x, acc.x);
                acc.y = fmaf(s, w.y, acc.y);
                acc.z = fmaf(s, w.z, acc.z);
                acc.w = fmaf(s, w.w, acc.w);
            }
#pragma unroll
            for (int off = 16; off <= 32; off <<= 1) {
                acc.x += __shfl_xor(acc.x, off, 64);
                acc.y += __shfl_xor(acc.y, off, 64);
                acc.z += __shfl_xor(acc.z, off, 64);
                acc.w += __shfl_xor(acc.w, off, 64);
            }
            if (r == 0) *(float4*)&partial[par][wv][4 * q] = acc;
        }
        __syncthreads();                       // partial ready; peL[par] consumed
        // publish (fire-and-forget sc1) ...
        if (t < 64) {
            const int nv = t >> 5;
            const int j2 = t & 31;
            const int jj = j2 * 2;
            const int ru = rules[l * PP + nb0 + nv];
            float h0 = partial[par][2 * nv][jj]     + partial[par][2 * nv + 1][jj]
                     + b_rule[ru * DD + jj];
            float h1 = partial[par][2 * nv][jj + 1] + partial[par][2 * nv + 1][jj + 1]
                     + b_rule[ru * DD + jj + 1];
            F2U cv;
            cv.f.x = fmaxf(h0, 0.f);
            cv.f.y = fmaxf(h1, 0.f);
            cv.u &= SIGN_CLR;          // published sign bits must be 0
            stull(&dstore_u[((size_t)l * PP + nb0 + nv) * 32 + j2], cv.u);
        }
        // ... overlapped with speculative gather of level l+2 into buf[par]
        if (l + 2 < LVLS && t < 128) {
            int pid = parents[((size_t)(l + 2) * PP + nb0) * 2 + grow];
            F2U cv; bool bad = false;
            if (pid < N_INIT) {
                cv.f = ((const float2*)init_table)[(size_t)thax[pid] * 32 + gj];
            } else {
                cv.u = ldull(&dstore_u[(size_t)(pid - N_INIT) * 32 + gj]);
                bad = (cv.u & SENT_MASK) != 0ull;
            }
            ((float2*)&peL[par][grow >> 1][(grow & 1) * DD])[gj] = cv.f;
            if (par) { pend1 = bad; pid1 = pid; }
            else     { pend0 = bad; pid0 = pid; }
        }
    }

    // ---------------- phase 3: gate on mask counts ----------------
    if (t == 0) { while (ldi(init_done) < NBLK) __builtin_amdgcn_s_sleep(1); }
    __syncthreads();
    const int ng = ldi(&acc_i[0]);
    const int ns = ldi(&acc_i[1]);
    const int nn = ns - ng;
    const float pos_w = ng > 0 ? 0.85f / (float)ng : 1.0f;
    const float neg_w = nn > 0 ? 0.15f / (float)nn : 1.0f;

    // ---------------- phase 4: eval + loss (r15 math, dynamic tile claim) ----------------
    const int g  = t & 31;
    const int n0 = t >> 5;
    const float4* __restrict__ W14 = (const float4*)W1;
    const float4 b1v = ((const float4*)b1)[g];
    const float4 w2v = ((const float4*)w2)[g];
    const float  b2v = b2[0];

    float loss = 0.f;
    int cp = 0, cn = 0;

    for (;;) {
        if (t == 0) s_tile = atomicAdd(tile_claim, 1);
        __syncthreads();
        const int tile = s_tile;
        if (tile >= NTILES) break;
        const int base = tile * 64;
        const int nv = (N_TOT - base < 64) ? (N_TOT - base) : 64;
        for (int idx = t; idx < 64 * 32; idx += NTHR) {
            int n = idx >> 5, j = idx & 31;
            int node = base + n;
            float2 v = make_float2(0.f, 0.f);
            if (n < nv) {
                if (node < N_INIT)
                    v = ((const float2*)init_table)[(size_t)thax[node] * 32 + j];
                else
                    v = ld_hyb(&dstore_u[(size_t)(node - N_INIT) * 32 + j]);
            }
            ((float2*)sS[n])[j] = v;
        }
        __syncthreads();

        float4 a[8];
#pragma unroll
        for (int k = 0; k < 8; ++k) a[k] = b1v;
#pragma unroll
        for (int d4 = 0; d4 < 16; ++d4) {
            float4 w0  = W14[(d4 * 4 + 0) * 32 + g];
            float4 w1  = W14[(d4 * 4 + 1) * 32 + g];
            float4 w2q = W14[(d4 * 4 + 2) * 32 + g];
            float4 w3  = W14[(d4 * 4 + 3) * 32 + g];
#pragma unroll
            for (int k = 0; k < 8; ++k) {
                float4 s = ((const float4*)sS[n0 + 8 * k])[d4];
                a[k].x = fmaf(s.x, w0.x, a[k].x); a[k].y = fmaf(s.x, w0.y, a[k].y);
                a[k].z = fmaf(s.x, w0.z, a[k].z); a[k].w = fmaf(s.x, w0.w, a[k].w);
                a[k].x = fmaf(s.y, w1.x, a[k].x); a[k].y = fmaf(s.y, w1.y, a[k].y);
                a[k].z = fmaf(s.y, w1.z, a[k].z); a[k].w = fmaf(s.y, w1.w, a[k].w);
                a[k].x = fmaf(s.z, w2q.x, a[k].x); a[k].y = fmaf(s.z, w2q.y, a[k].y);
                a[k].z = fmaf(s.z, w2q.z, a[k].z); a[k].w = fmaf(s.z, w2q.w, a[k].w);
                a[k].x = fmaf(s.w, w3.x, a[k].x); a[k].y = fmaf(s.w, w3.y, a[k].y);
                a[k].z = fmaf(s.w, w3.z, a[k].z); a[k].w = fmaf(s.w, w3.w, a[k].w);
            }
        }
        float p[8];
#pragma unroll
        for (int k = 0; k < 8; ++k) {
            p[k] = fmaxf(a[k].x, 0.f) * w2v.x + fmaxf(a[k].y, 0.f) * w2v.y +
                   fmaxf(a[k].z, 0.f) * w2v.z + fmaxf(a[k].w, 0.f) * w2v.w;
#pragma unroll
            for (int off = 1; off < 32; off <<= 1)
                p[k] += __shfl_xor(p[k], off, 32);
        }
        if (g == 0) {
#pragma unroll
            for (int k = 0; k < 8; ++k)
                logitL[n0 + 8 * k] = p[k] + b2v;
        }
        __syncthreads();

        if (t < 64) {
            int node = base + t;
            bool valid = t < nv;
            float lg = logitL[t];
            bool sel  = valid && sel_mask[node] > 0;
            bool good = sel && good_mask[node] > 0;
            float bce = softplusf(lg) - lg * (good ? 1.f : 0.f);
            float w   = (good ? pos_w : neg_w) * (sel ? 1.f : 0.f);
            loss += valid ? w * bce : 0.f;
            cp += (good && lg >= 0.f) ? 1 : 0;
            cn += (sel && !good && lg < 0.f) ? 1 : 0;
        }
        __syncthreads();     // logitL/sS safe for reuse + s_tile rewrite
    }

    // ---------------- phase 5: reduce + finalize ----------------
    {
        __shared__ float wsum[4];
        __shared__ int   wcp[4], wcn[4];
        float c = loss;
        int cpp = cp, cnn = cn;
#pragma unroll
        for (int off = 32; off; off >>= 1) {
            c   += __shfl_down(c, off, 64);
            cpp += __shfl_down(cpp, off, 64);
            cnn += __shfl_down(cnn, off, 64);
        }
        if (lane == 0) { wsum[wv] = c; wcp[wv] = cpp; wcn[wv] = cnn; }
        __syncthreads();
        if (t == 0) {
            float ct = wsum[0] + wsum[1] + wsum[2] + wsum[3];
            int cpt = wcp[0] + wcp[1] + wcp[2] + wcp[3];
            int cnt = wcn[0] + wcn[1] + wcn[2] + wcn[3];
            atomicAdd(acc_f, ct);
            if (cpt) atomicAdd(&acc_i[2], cpt);
            if (cnt) atomicAdd(&acc_i[3], cnt);
            vm0();
            int d = atomicAdd(fin_done, 1);
            if (d == NBLK - 1) {
                int ng2 = ldi(&acc_i[0]);
                int ns2 = ldi(&acc_i[1]);
                int cp2 = ldi(&acc_i[2]);
                int cn2 = ldi(&acc_i[3]);
                float lf = ldf(acc_f);
                int nn2 = ns2 - ng2;
                out[0] = lf;
                out[1] = ng2 > 0 ? (float)cp2 / (float)ng2 : 1.0f;
                out[2] = nn2 > 0 ? (float)cn2 / (float)nn2 : 1.0f;
            }
        }
    }
}

extern "C" void kernel_launch(void* const* d_in, const int* in_sizes, int n_in,
                              void* d_out, int out_size, void* d_ws, size_t ws_size,
                              hipStream_t stream) {
    const int*   thax       = (const int*)d_in[0];
    const int*   parents    = (const int*)d_in[1];
    const int*   rules      = (const int*)d_in[2];
    const int*   sel_mask   = (const int*)d_in[3];
    const int*   good_mask  = (const int*)d_in[4];
    const float* init_table = (const float*)d_in[5];
    const float* W_rule     = (const float*)d_in[6];
    const float* b_rule     = (const float*)d_in[7];
    const float* W1         = (const float*)d_in[8];
    const float* b1         = (const float*)d_in[9];
    const float* w2         = (const float*)d_in[10];
    const float* b2         = (const float*)d_in[11];

    // ctl -> 0 ; dstore -> 0xFF (negative-NaN sentinel, sign bit 1)
    hipMemsetAsync(d_ws, 0, 256, stream);
    hipMemsetAsync((char*)d_ws + DSTORE_OFF, 0xFF, (size_t)ND * DD * 4, stream);

    persist14<<<NBLK, NTHR, 0, stream>>>(
        thax, parents, rules, sel_mask, good_mask, init_table,
        W_rule, b_rule, W1, b1, w2, b2,
        (char*)d_ws, (float*)d_out);
}

// Round 19
// 173.852 us; speedup vs baseline: 1.3958x; 1.1514x over previous
//
#include <hip/hip_runtime.h>
#include <math.h>

#define N_INIT 20000
#define LVLS   32
#define PP     1024
#define DD     64
#define DEE    128
#define N_TOT  (N_INIT + LVLS * PP)   // 52768
#define ND     (LVLS * PP)            // 32768 derived nodes
#define NBLK   512                    // 2 blocks/CU, co-residency proven r8-r14
#define NTHR   256
#define NPB    2                      // nodes per block per level
#define NTILES ((N_TOT + 63) / 64)    // 825 eval tiles

// ws layout:
// [0,256) ctl: acc_i[4]@0, acc_f@16, init_done@20, fin_done@24
// [256, 256+ND*DD*4)  dstore (memset 0xFF each call: negative-NaN sentinel)
#define DSTORE_OFF 256

typedef unsigned long long ull;
union F2U { ull u; float2 f; };
#define SENT_MASK 0x8000000080000000ULL
#define SIGN_CLR  0x7FFFFFFF7FFFFFFFULL

// ---- device-coherent accessors (AGENT scope), proven r5-r18 ----
__device__ __forceinline__ int ldi(const int* p) {
    return __hip_atomic_load(p, __ATOMIC_RELAXED, __HIP_MEMORY_SCOPE_AGENT);
}
__device__ __forceinline__ float ldf(const float* p) {
    return __hip_atomic_load(p, __ATOMIC_RELAXED, __HIP_MEMORY_SCOPE_AGENT);
}
__device__ __forceinline__ ull ldull(const ull* p) {
    return __hip_atomic_load(p, __ATOMIC_RELAXED, __HIP_MEMORY_SCOPE_AGENT);
}
__device__ __forceinline__ void stull(ull* p, ull v) {
    __hip_atomic_store(p, v, __ATOMIC_RELAXED, __HIP_MEMORY_SCOPE_AGENT);
}
__device__ __forceinline__ void vm0() {
    asm volatile("s_waitcnt vmcnt(0)" ::: "memory");
}
__device__ __forceinline__ float softplusf(float x) {
    return fmaxf(x, 0.f) + log1pf(expf(-fabsf(x)));
}
// blocking read of a published float2 (r11-proven): cached try, coherent spin fallback
__device__ __forceinline__ float2 ld_hyb(const ull* p) {
    F2U cv;
    cv.u = *p;
    if (cv.u & SENT_MASK) {
        cv.u = ldull(p);
        while (cv.u & SENT_MASK) {
            __builtin_amdgcn_s_sleep(1);
            cv.u = ldull(p);
        }
    }
    return cv.f;
}

__global__ __launch_bounds__(NTHR, 2) void persist11(
    const int* __restrict__ thax, const int* __restrict__ parents,
    const int* __restrict__ rules, const int* __restrict__ sel_mask,
    const int* __restrict__ good_mask, const float* __restrict__ init_table,
    const float* __restrict__ W_rule, const float* __restrict__ b_rule,
    const float* __restrict__ W1, const float* __restrict__ b1,
    const float* __restrict__ w2, const float* __restrict__ b2,
    char* __restrict__ ws, float* __restrict__ out)
{
    int*   acc_i     = (int*)ws;
    float* acc_f     = (float*)(ws + 16);
    int*   init_done = (int*)(ws + 20);
    int*   fin_done  = (int*)(ws + 24);
    ull*   dstore_u  = (ull*)(ws + DSTORE_OFF);

    const int b = blockIdx.x, t = threadIdx.x;
    const int lane = t & 63, wv = t >> 6;

    __shared__ float peL[2][NPB][2 * DD];   // 2 KB (depth-2 pipeline buffers)
    __shared__ float partial[2][4][DD];     // 2 KB (double-buffered by level parity)
    __shared__ float sS[64][DD];            // 16 KB (eval)
    __shared__ float logitL[64];

    // ---------------- phase 1: mask counts (r9 verbatim) ----------------
    {
        int idx = b * NTHR + t;
        bool v = idx < N_TOT;
        bool sel  = v && sel_mask[idx] > 0;
        bool good = sel && good_mask[idx] > 0;
        unsigned long long ms = __ballot(sel), mg = __ballot(good);
        if (lane == 0) {
            if (mg) atomicAdd(&acc_i[0], (int)__popcll(mg));
            if (ms) atomicAdd(&acc_i[1], (int)__popcll(ms));
        }
    }
    vm0();
    __syncthreads();
    if (t == 0) atomicAdd(init_done, 1);

    // ---------------- phase 2: depth-2 pipelined level loop ----------------
    const int nb0 = b * NPB;
    // per-thread (t<128) speculative-gather state for each parity buffer
    bool pend0 = false, pend1 = false;
    int  pid0 = 0,      pid1 = 0;
    const int grow = t >> 5, gj = t & 31;   // gather thread's (row, float2-elem)

    // prologue: gather level 0 (blocking-free: all parents < N_INIT)
    if (t < 128) {
        int pid = parents[(size_t)nb0 * 2 + grow];
        float2 v = ((const float2*)init_table)[(size_t)thax[pid] * 32 + gj];
        ((float2*)&peL[0][grow >> 1][(grow & 1) * DD])[gj] = v;
    }
    // prologue: speculative gather level 1 into buf1 (non-blocking)
    if (t < 128) {
        int pid = parents[((size_t)PP + nb0) * 2 + grow];
        F2U cv; bool bad = false;
        if (pid < N_INIT) {
            cv.f = ((const float2*)init_table)[(size_t)thax[pid] * 32 + gj];
        } else {
            cv.u = ldull(&dstore_u[(size_t)(pid - N_INIT) * 32 + gj]);
            bad = (cv.u & SENT_MASK) != 0ull;
        }
        ((float2*)&peL[1][grow >> 1][(grow & 1) * DD])[gj] = cv.f;
        pend1 = bad; pid1 = pid;
    }

    for (int l = 0; l < LVLS; ++l) {
        const int par = l & 1;
        // fixup: re-fetch stale words of this level's buffer (rare; bounded spin)
        if (t < 128) {
            bool pend = par ? pend1 : pend0;
            if (pend) {
                int pid = par ? pid1 : pid0;
                float2 v = ld_hyb(&dstore_u[(size_t)(pid - N_INIT) * 32 + gj]);
                ((float2*)&peL[par][grow >> 1][(grow & 1) * DD])[gj] = v;
                if (par) pend1 = false; else pend0 = false;
            }
        }
        __syncthreads();                       // peL[par] final
        // compute: waves {0,1}->node 0, {2,3}->node 1; half = wv&1 covers 64 rows
        {
            const int nv = wv >> 1, half = wv & 1;
            const int ru = rules[l * PP + nb0 + nv];
            const float4* __restrict__ W4 =
                (const float4*)W_rule + (size_t)ru * 2048 + (size_t)half * 64 * 16;
            const int q = lane & 15, r = lane >> 4;
            const float* pk = &peL[par][nv][half * DD];
            float4 acc = make_float4(0.f, 0.f, 0.f, 0.f);
#pragma unroll
            for (int i = 0; i < 16; ++i) {
                float4 w = W4[(i * 4 + r) * 16 + q];
                float  s = pk[i * 4 + r];
                acc.x = fmaf(s, w.x, acc.x);
                acc.y = fmaf(s, w.y, acc.y);
                acc.z = fmaf(s, w.z, acc.z);
                acc.w = fmaf(s, w.w, acc.w);
            }
#pragma unroll
            for (int off = 16; off <= 32; off <<= 1) {
                acc.x += __shfl_xor(acc.x, off, 64);
                acc.y += __shfl_xor(acc.y, off, 64);
                acc.z += __shfl_xor(acc.z, off, 64);
                acc.w += __shfl_xor(acc.w, off, 64);
            }
            if (r == 0) *(float4*)&partial[par][wv][4 * q] = acc;
        }
        __syncthreads();                       // partial ready; peL[par] consumed
        // publish (fire-and-forget sc1) ...
        if (t < 64) {
            const int nv = t >> 5;
            const int j2 = t & 31;
            const int jj = j2 * 2;
            const int ru = rules[l * PP + nb0 + nv];
            float h0 = partial[par][2 * nv][jj]     + partial[par][2 * nv + 1][jj]
                     + b_rule[ru * DD + jj];
            float h1 = partial[par][2 * nv][jj + 1] + partial[par][2 * nv + 1][jj + 1]
                     + b_rule[ru * DD + jj + 1];
            F2U cv;
            cv.f.x = fmaxf(h0, 0.f);
            cv.f.y = fmaxf(h1, 0.f);
            cv.u &= SIGN_CLR;          // published sign bits must be 0
            stull(&dstore_u[((size_t)l * PP + nb0 + nv) * 32 + j2], cv.u);
        }
        // ... overlapped with speculative gather of level l+2 into buf[par]
        if (l + 2 < LVLS && t < 128) {
            int pid = parents[((size_t)(l + 2) * PP + nb0) * 2 + grow];
            F2U cv; bool bad = false;
            if (pid < N_INIT) {
                cv.f = ((const float2*)init_table)[(size_t)thax[pid] * 32 + gj];
            } else {
                cv.u = ldull(&dstore_u[(size_t)(pid - N_INIT) * 32 + gj]);
                bad = (cv.u & SENT_MASK) != 0ull;
            }
            ((float2*)&peL[par][grow >> 1][(grow & 1) * DD])[gj] = cv.f;
            if (par) { pend1 = bad; pid1 = pid; }
            else     { pend0 = bad; pid0 = pid; }
        }
    }

    // ---------------- phase 3: gate on mask counts ----------------
    if (t == 0) { while (ldi(init_done) < NBLK) __builtin_amdgcn_s_sleep(1); }
    __syncthreads();
    const int ng = ldi(&acc_i[0]);
    const int ns = ldi(&acc_i[1]);
    const int nn = ns - ng;
    const float pos_w = ng > 0 ? 0.85f / (float)ng : 1.0f;
    const float neg_w = nn > 0 ? 0.15f / (float)nn : 1.0f;

    // ---------------- phase 4: eval + loss (r11 verbatim) ----------------
    const int g  = t & 31;
    const int n0 = t >> 5;
    const float4* __restrict__ W14 = (const float4*)W1;
    const float4 b1v = ((const float4*)b1)[g];
    const float4 w2v = ((const float4*)w2)[g];
    const float  b2v = b2[0];

    float loss = 0.f;
    int cp = 0, cn = 0;

    for (int tile = b; tile < NTILES; tile += NBLK) {
        const int base = tile * 64;
        const int nv = (N_TOT - base < 64) ? (N_TOT - base) : 64;
        for (int idx = t; idx < 64 * 32; idx += NTHR) {
            int n = idx >> 5, j = idx & 31;
            int node = base + n;
            float2 v = make_float2(0.f, 0.f);
            if (n < nv) {
                if (node < N_INIT)
                    v = ((const float2*)init_table)[(size_t)thax[node] * 32 + j];
                else
                    v = ld_hyb(&dstore_u[(size_t)(node - N_INIT) * 32 + j]);
            }
            ((float2*)sS[n])[j] = v;
        }
        __syncthreads();

        float4 a[8];
#pragma unroll
        for (int k = 0; k < 8; ++k) a[k] = b1v;
#pragma unroll
        for (int d4 = 0; d4 < 16; ++d4) {
            float4 w0  = W14[(d4 * 4 + 0) * 32 + g];
            float4 w1  = W14[(d4 * 4 + 1) * 32 + g];
            float4 w2q = W14[(d4 * 4 + 2) * 32 + g];
            float4 w3  = W14[(d4 * 4 + 3) * 32 + g];
#pragma unroll
            for (int k = 0; k < 8; ++k) {
                float4 s = ((const float4*)sS[n0 + 8 * k])[d4];
                a[k].x = fmaf(s.x, w0.x, a[k].x); a[k].y = fmaf(s.x, w0.y, a[k].y);
                a[k].z = fmaf(s.x, w0.z, a[k].z); a[k].w = fmaf(s.x, w0.w, a[k].w);
                a[k].x = fmaf(s.y, w1.x, a[k].x); a[k].y = fmaf(s.y, w1.y, a[k].y);
                a[k].z = fmaf(s.y, w1.z, a[k].z); a[k].w = fmaf(s.y, w1.w, a[k].w);
                a[k].x = fmaf(s.z, w2q.x, a[k].x); a[k].y = fmaf(s.z, w2q.y, a[k].y);
                a[k].z = fmaf(s.z, w2q.z, a[k].z); a[k].w = fmaf(s.z, w2q.w, a[k].w);
                a[k].x = fmaf(s.w, w3.x, a[k].x); a[k].y = fmaf(s.w, w3.y, a[k].y);
                a[k].z = fmaf(s.w, w3.z, a[k].z); a[k].w = fmaf(s.w, w3.w, a[k].w);
            }
        }
        float p[8];
#pragma unroll
        for (int k = 0; k < 8; ++k) {
            p[k] = fmaxf(a[k].x, 0.f) * w2v.x + fmaxf(a[k].y, 0.f) * w2v.y +
                   fmaxf(a[k].z, 0.f) * w2v.z + fmaxf(a[k].w, 0.f) * w2v.w;
#pragma unroll
            for (int off = 1; off < 32; off <<= 1)
                p[k] += __shfl_xor(p[k], off, 32);
        }
        if (g == 0) {
#pragma unroll
            for (int k = 0; k < 8; ++k)
                logitL[n0 + 8 * k] = p[k] + b2v;
        }
        __syncthreads();

        if (t < 64) {
            int node = base + t;
            bool valid = t < nv;
            float lg = logitL[t];
            bool sel  = valid && sel_mask[node] > 0;
            bool good = sel && good_mask[node] > 0;
            float bce = softplusf(lg) - lg * (good ? 1.f : 0.f);
            float w   = (good ? pos_w : neg_w) * (sel ? 1.f : 0.f);
            loss += valid ? w * bce : 0.f;
            cp += (good && lg >= 0.f) ? 1 : 0;
            cn += (sel && !good && lg < 0.f) ? 1 : 0;
        }
        __syncthreads();
    }

    // ---------------- phase 5: reduce + finalize (r9 verbatim) ----------------
    if (t < 64) {
        float c = loss;
        int cpp = cp, cnn = cn;
#pragma unroll
        for (int off = 32; off; off >>= 1) {
            c   += __shfl_down(c, off, 64);
            cpp += __shfl_down(cpp, off, 64);
            cnn += __shfl_down(cnn, off, 64);
        }
        if (t == 0) {
            atomicAdd(acc_f, c);
            if (cpp) atomicAdd(&acc_i[2], cpp);
            if (cnn) atomicAdd(&acc_i[3], cnn);
            vm0();
            int d = atomicAdd(fin_done, 1);
            if (d == NBLK - 1) {
                int ng2 = ldi(&acc_i[0]);
                int ns2 = ldi(&acc_i[1]);
                int cp2 = ldi(&acc_i[2]);
                int cn2 = ldi(&acc_i[3]);
                float lf = ldf(acc_f);
                int nn2 = ns2 - ng2;
                out[0] = lf;
                out[1] = ng2 > 0 ? (float)cp2 / (float)ng2 : 1.0f;
                out[2] = nn2 > 0 ? (float)cn2 / (float)nn2 : 1.0f;
            }
        }
    }
}

extern "C" void kernel_launch(void* const* d_in, const int* in_sizes, int n_in,
                              void* d_out, int out_size, void* d_ws, size_t ws_size,
                              hipStream_t stream) {
    const int*   thax       = (const int*)d_in[0];
    const int*   parents    = (const int*)d_in[1];
    const int*   rules      = (const int*)d_in[2];
    const int*   sel_mask   = (const int*)d_in[3];
    const int*   good_mask  = (const int*)d_in[4];
    const float* init_table = (const float*)d_in[5];
    const float* W_rule     = (const float*)d_in[6];
    const float* b_rule     = (const float*)d_in[7];
    const float* W1         = (const float*)d_in[8];
    const float* b1         = (const float*)d_in[9];
    const float* w2         = (const float*)d_in[10];
    const float* b2         = (const float*)d_in[11];

    // ctl -> 0 ; dstore -> 0xFF (negative-NaN sentinel, sign bit 1)
    hipMemsetAsync(d_ws, 0, 256, stream);
    hipMemsetAsync((char*)d_ws + DSTORE_OFF, 0xFF, (size_t)ND * DD * 4, stream);

    persist11<<<NBLK, NTHR, 0, stream>>>(
        thax, parents, rules, sel_mask, good_mask, init_table,
        W_rule, b_rule, W1, b1, w2, b2,
        (char*)d_ws, (float*)d_out);
}